// Round 13
// baseline (661.172 us; speedup 1.0000x reference)
//
#include <hip/hip_runtime.h>

#define DEVI __device__ __forceinline__

typedef unsigned short u16;
typedef unsigned int u32;
typedef __attribute__((ext_vector_type(8))) short s16x8;
typedef __attribute__((ext_vector_type(4))) float f32x4;
typedef __attribute__((ext_vector_type(4))) unsigned short u16x4v;
typedef __attribute__((ext_vector_type(4))) unsigned int u32x4;

constexpr int NB   = 16;
constexpr int LL   = 512;
constexpr int DD   = 512;
constexpr int FF_  = 2048;
constexpr int NROW = NB * LL;                  // 8192
constexpr float C2 = 0.17677669529663687f * 1.4426950408889634f; // scale*log2(e)
constexpr size_t QKVOFF = (size_t)NROW * DD;   // elems per Q/K/V segment

DEVI u16 f2b(float f) {
  unsigned int u = __float_as_uint(f);
  unsigned int r = u + 0x7FFFu + ((u >> 16) & 1u); // RNE
  return (u16)(r >> 16);
}

// async global->LDS, 16B per lane; LDS dest = uniform base + lane*16
DEVI void gload16(const void* g, void* l) {
  __builtin_amdgcn_global_load_lds(
      (const __attribute__((address_space(1))) unsigned int*)(unsigned long long)g,
      (__attribute__((address_space(3))) unsigned int*)(unsigned int)(unsigned long long)l,
      16, 0, 0);
}

// ---------------- elementwise helpers ----------------
__global__ __launch_bounds__(256) void k_f32_to_bf16(const float* __restrict__ X, u16* __restrict__ Y, int n4) {
  for (int i = blockIdx.x * 256 + threadIdx.x; i < n4; i += gridDim.x * 256) {
    float4 x = ((const float4*)X)[i];
    u16x4v o; o[0] = f2b(x.x); o[1] = f2b(x.y); o[2] = f2b(x.z); o[3] = f2b(x.w);
    ((u16x4v*)Y)[i] = o;
  }
}

__global__ __launch_bounds__(256) void k_zero(float* __restrict__ p, int n) {
  int i = blockIdx.x * 256 + threadIdx.x;
  if (i < n) p[i] = 0.f;
}

__global__ __launch_bounds__(256) void k_recip(float* __restrict__ p, int n) {
  int i = blockIdx.x * 256 + threadIdx.x;
  if (i < n) p[i] = 1.0f / p[i];
}

__global__ void k_catbias(const float* __restrict__ a, const float* __restrict__ b,
                          const float* __restrict__ c, float* __restrict__ o) {
  int i = blockIdx.x * 256 + threadIdx.x; // 1536
  o[i] = (i < 512) ? a[i] : (i < 1024) ? b[i - 512] : c[i - 1024];
}

// ---------------- weight transpose + convert: WT[m*K+k] = bf16(W[k*M+m]) ----------------
__global__ __launch_bounds__(256) void k_wtrans(const float* __restrict__ W, u16* __restrict__ WT, int K, int M) {
  __shared__ float tile[32][33];
  const int k0 = blockIdx.x * 32, m0 = blockIdx.y * 32;
  const int tx = threadIdx.x & 31, ty = threadIdx.x >> 5;
#pragma unroll
  for (int j = 0; j < 4; ++j) tile[ty + j * 8][tx] = W[(size_t)(k0 + ty + j * 8) * M + m0 + tx];
  __syncthreads();
#pragma unroll
  for (int j = 0; j < 4; ++j) WT[(size_t)(m0 + ty + j * 8) * K + k0 + tx] = f2b(tile[tx][ty + j * 8]);
}

// ---------------- GEMM: C = act(A.Bt + bias) [+ BN(Res)] ----------------
template <int BM, int DBUF, int RELU, int HASB, int HASRES, int RESBN, int OUTF, int OUTB, int STATS, int SPLIT3>
__global__ __launch_bounds__(256) void k_gemm(const u16* __restrict__ A, const u16* __restrict__ Bt,
                                              const float* __restrict__ bias, const float* Res,
                                              const float* __restrict__ resco,
                                              float* Cf, u16* __restrict__ Cb,
                                              float* __restrict__ stats, int K, int Ncols) {
  constexpr int WR = BM / 64;
  constexpr int WC = 4 / WR;
  constexpr int MW = 4;
  constexpr int NW = 128 / (16 * WC);
  __shared__ __align__(16) u16 As[(DBUF ? 2 : 1) * BM * 64];
  __shared__ __align__(16) u16 Bs[(DBUF ? 2 : 1) * 128 * 64];
  const int t = threadIdx.x, lane = t & 63, w = t >> 6;
  const int wr = w / WC, wc = w % WC, l16 = lane & 15, lhi = lane >> 4;
  const int row0 = blockIdx.x * BM, col0 = blockIdx.y * 128;
  const int sr = lane >> 3, sc = (lane & 7) * 8;
  const u16* Ag = A + (size_t)(row0 + sr) * K + sc;
  const u16* Bg = Bt + (size_t)(col0 + sr) * K + sc;

  f32x4 acc[MW][NW] = {};

  auto stage = [&](int buf, int k0) {
    u16* Ad = As + buf * (BM * 64);
    u16* Bd = Bs + buf * (128 * 64);
#pragma unroll
    for (int j = 0; j < BM / 32; ++j) {
      const int ch = w * (BM / 32) + j;
      gload16(Ag + (size_t)(ch * 8) * K + k0, Ad + ch * 512);
    }
#pragma unroll
    for (int j = 0; j < 4; ++j) {
      const int ch = w * 4 + j;
      gload16(Bg + (size_t)(ch * 8) * K + k0, Bd + ch * 512);
    }
  };

  auto compute = [&](const u16* Ab, const u16* Bb) {
#pragma unroll
    for (int kk = 0; kk < 2; ++kk) {
      s16x8 af[MW], bfv[NW];
#pragma unroll
      for (int m = 0; m < MW; ++m) af[m] = *(const s16x8*)(Ab + (wr * 64 + m * 16 + l16) * 64 + kk * 32 + lhi * 8);
#pragma unroll
      for (int n = 0; n < NW; ++n) bfv[n] = *(const s16x8*)(Bb + (wc * (16 * NW) + n * 16 + l16) * 64 + kk * 32 + lhi * 8);
#pragma unroll
      for (int m = 0; m < MW; ++m)
#pragma unroll
        for (int n = 0; n < NW; ++n)
          acc[m][n] = __builtin_amdgcn_mfma_f32_16x16x32_bf16(af[m], bfv[n], acc[m][n], 0, 0, 0);
    }
  };

  if constexpr (DBUF) {
    stage(0, 0);
    const int NT = K >> 6;
    for (int kt = 0; kt < NT; ++kt) {
      const int cur = kt & 1;
      __syncthreads();
      if (kt + 1 < NT) stage(cur ^ 1, (kt + 1) << 6);
      compute(As + cur * (BM * 64), Bs + cur * (128 * 64));
    }
  } else {
    for (int k0 = 0; k0 < K; k0 += 64) {
      __syncthreads();
      stage(0, k0);
      __syncthreads();
      compute(As, Bs);
    }
  }

#pragma unroll
  for (int n = 0; n < NW; ++n) {
    const int col = col0 + wc * (16 * NW) + n * 16 + l16;
    float bv = 0.f;
    if constexpr (HASB) bv = bias[col];
    float ra = 0.f, rc = 0.f;
    if constexpr (RESBN) { ra = resco[col]; rc = resco[512 + col]; }
    float ssum = 0.f, ssq = 0.f;
#pragma unroll
    for (int m = 0; m < MW; ++m) {
      const int rbase = row0 + wr * 64 + m * 16 + lhi * 4;
#pragma unroll
      for (int r = 0; r < 4; ++r) {
        float v = acc[m][n][r] + bv;
        if constexpr (RELU) v = fmaxf(v, 0.f);
        const int row = rbase + r;
        const size_t idx = (size_t)row * Ncols + col;
        if constexpr (HASRES) {
          if constexpr (RESBN) v += fmaf(Res[idx], ra, rc);
          else v += Res[idx];
        }
        if constexpr (OUTF) Cf[idx] = v;
        if constexpr (OUTB) {
          if constexpr (SPLIT3) {
            const size_t ib = (size_t)(col >> 9) * QKVOFF + (size_t)row * DD + (col & 511);
            Cb[ib] = f2b(v);
          } else {
            Cb[idx] = f2b(v);
          }
        }
        if constexpr (STATS) { ssum += v; ssq += v * v; }
      }
    }
    if constexpr (STATS) {
      ssum += __shfl_xor(ssum, 16); ssq += __shfl_xor(ssq, 16);
      ssum += __shfl_xor(ssum, 32); ssq += __shfl_xor(ssq, 32);
      if (lhi == 0) {
        atomicAdd(&stats[col], ssum);
        atomicAdd(&stats[512 + col], ssq);
      }
    }
  }
}

// ---------------- attention pass 1: Z[q,k] = sum_n exp(scale * Q_[n,q,:].K_[n,k,:]) ----------------
__global__ __launch_bounds__(256) void k_attn_z(const u16* __restrict__ Q, const u16* __restrict__ Kt,
                                                float* __restrict__ Z) {
  const int t = threadIdx.x, lane = t & 63, w = t >> 6;
  const int l16 = lane & 15, lhi = lane >> 4;
  const int q0 = blockIdx.x * 64 + (w >> 1) * 32;
  const int k0 = blockIdx.y * 64 + (w & 1) * 32;
  const int n0 = blockIdx.z * 16;
  f32x4 zac[2][2] = {};
  for (int nn = 0; nn < 16; ++nn) {
    const int n = n0 + nn, h = n >> 4, b = n & 15;
    const size_t base = (size_t)b * LL * DD + (size_t)h * 32;
    s16x8 a[2], bb[2];
#pragma unroll
    for (int mi = 0; mi < 2; ++mi) a[mi] = *(const s16x8*)(Q + base + (size_t)(q0 + mi * 16 + l16) * DD + lhi * 8);
#pragma unroll
    for (int ni = 0; ni < 2; ++ni) bb[ni] = *(const s16x8*)(Kt + base + (size_t)(k0 + ni * 16 + l16) * DD + lhi * 8);
#pragma unroll
    for (int mi = 0; mi < 2; ++mi)
#pragma unroll
      for (int ni = 0; ni < 2; ++ni) {
        f32x4 z4 = {0.f, 0.f, 0.f, 0.f};
        f32x4 s = __builtin_amdgcn_mfma_f32_16x16x32_bf16(a[mi], bb[ni], z4, 0, 0, 0);
#pragma unroll
        for (int r = 0; r < 4; ++r) zac[mi][ni][r] += exp2f(s[r] * C2);
      }
  }
#pragma unroll
  for (int mi = 0; mi < 2; ++mi)
#pragma unroll
    for (int ni = 0; ni < 2; ++ni)
#pragma unroll
      for (int r = 0; r < 4; ++r)
        atomicAdd(&Z[(q0 + mi * 16 + lhi * 4 + r) * LL + k0 + ni * 16 + l16], zac[mi][ni][r]);
}

// ---------------- attention pass 2 (pv3): K/V LDS-resident, P transposed IN-REGISTER ----------------
// Swapped QK^T leaves P[q=l16][k=ks*16+lhi*4+r] per lane. The PV A-fragment needs
// P[q=l16][k=kc*32+lhi*8+e] — same l16, data moves only across lhi (lane bits 4-5):
//   a=W[2kc][h]; b=W[2kc+1][h]; permlane32_swap(a,b); permlane16_swap(a,b)
// leaves a = A-words, b = B-words of the fragment. No LDS P buffer, no lgkmcnt link.
__global__ __launch_bounds__(1024) void k_attn_pv3(const u16* __restrict__ Q, const u16* __restrict__ K,
                                                   const u16* __restrict__ V, const float* __restrict__ IZ,
                                                   const float* __restrict__ resco, float* T,
                                                   float* __restrict__ stats) {
  __shared__ __align__(16) u16 Kl[512 * 40];   // rows padded 32->40 u16
  __shared__ __align__(16) u16 Vl[32 * 520];   // d-major rows padded 512->520 u16
  const int n = blockIdx.x, h = n >> 4, b = n & 15;
  const int t = threadIdx.x, lane = t & 63, w = t >> 6;
  const int l16 = lane & 15, lhi = lane >> 4;
  const size_t base = (size_t)b * LL * DD + (size_t)h * 32;

  // stage K: 2048 x 16B chunks (2 per thread)
#pragma unroll
  for (int j = 0; j < 2; ++j) {
    const int c = t + j * 1024;
    const int k = c >> 2, part = c & 3;
    const s16x8 v = *(const s16x8*)(K + base + (size_t)k * DD + part * 8);
    *(s16x8*)(Kl + k * 40 + part * 8) = v;
  }
  // stage V with in-flight transpose
#pragma unroll
  for (int j = 0; j < 2; ++j) {
    const int c = t + j * 1024;
    const int k = c >> 2, dp = c & 3;
    const s16x8 v = *(const s16x8*)(V + base + (size_t)k * DD + dp * 8);
#pragma unroll
    for (int jj = 0; jj < 8; ++jj) Vl[(dp * 8 + jj) * 520 + k] = (u16)v[jj];
  }
  // preload this wave's 2 Q fragments
  const int qbase = w * 32;
  s16x8 aqv[2];
#pragma unroll
  for (int qf = 0; qf < 2; ++qf)
    aqv[qf] = *(const s16x8*)(Q + base + (size_t)(qbase + qf * 16 + l16) * DD + lhi * 8);
  float ra[2], rc[2];
#pragma unroll
  for (int dt = 0; dt < 2; ++dt) {
    const int col = h * 32 + dt * 16 + l16;
    ra[dt] = resco[col]; rc[dt] = resco[512 + col];
  }
  __syncthreads();

  float ssum[2] = {0.f, 0.f}, ssq[2] = {0.f, 0.f};

#pragma unroll
  for (int qf = 0; qf < 2; ++qf) {
    const int q16 = qbase + qf * 16;
    const float* izrow = IZ + (size_t)(q16 + l16) * LL + lhi * 4;
    f32x4 oa[2] = {};
#pragma unroll
    for (int kt = 0; kt < 8; ++kt) {
      const int kb = kt * 64;
      f32x4 s[4]; float4 iz[4];
#pragma unroll
      for (int ks = 0; ks < 4; ++ks) {
        const s16x8 af = *(const s16x8*)(Kl + (kb + ks * 16 + l16) * 40 + lhi * 8);
        f32x4 z4 = {0.f, 0.f, 0.f, 0.f};
        s[ks] = __builtin_amdgcn_mfma_f32_16x16x32_bf16(af, aqv[qf], z4, 0, 0, 0);
        iz[ks] = *(const float4*)(izrow + kb + ks * 16);
      }
      // exp * invZ, pack to bf16 word-pairs per ks
      u32 W[4][2];
#pragma unroll
      for (int ks = 0; ks < 4; ++ks) {
        const float p0 = exp2f(s[ks][0] * C2) * iz[ks].x;
        const float p1 = exp2f(s[ks][1] * C2) * iz[ks].y;
        const float p2 = exp2f(s[ks][2] * C2) * iz[ks].z;
        const float p3 = exp2f(s[ks][3] * C2) * iz[ks].w;
        asm("v_cvt_pk_bf16_f32 %0, %1, %2" : "=v"(W[ks][0]) : "v"(p0), "v"(p1));
        asm("v_cvt_pk_bf16_f32 %0, %1, %2" : "=v"(W[ks][1]) : "v"(p2), "v"(p3));
      }
      // in-register transpose + PV
#pragma unroll
      for (int kc = 0; kc < 2; ++kc) {
        u32 a0 = W[2 * kc][0], b0 = W[2 * kc + 1][0];
        u32 a1 = W[2 * kc][1], b1 = W[2 * kc + 1][1];
        asm("v_permlane32_swap_b32 %0, %1" : "+v"(a0), "+v"(b0));
        asm("v_permlane32_swap_b32 %0, %1" : "+v"(a1), "+v"(b1));
        asm("v_permlane16_swap_b32 %0, %1" : "+v"(a0), "+v"(b0));
        asm("v_permlane16_swap_b32 %0, %1" : "+v"(a1), "+v"(b1));
        u32x4 paw; paw[0] = a0; paw[1] = a1; paw[2] = b0; paw[3] = b1;
        const s16x8 pa = __builtin_bit_cast(s16x8, paw);
#pragma unroll
        for (int dt = 0; dt < 2; ++dt) {
          const s16x8 bv = *(const s16x8*)(Vl + (dt * 16 + l16) * 520 + kb + kc * 32 + lhi * 8);
          oa[dt] = __builtin_amdgcn_mfma_f32_16x16x32_bf16(pa, bv, oa[dt], 0, 0, 0);
        }
      }
    }
#pragma unroll
    for (int dt = 0; dt < 2; ++dt)
#pragma unroll
      for (int r = 0; r < 4; ++r) {
        const size_t idx = (size_t)(b * LL + q16 + lhi * 4 + r) * DD + h * 32 + dt * 16 + l16;
        const float v = oa[dt][r] + fmaf(T[idx], ra[dt], rc[dt]);
        T[idx] = v;
        ssum[dt] += v; ssq[dt] += v * v;
      }
  }
#pragma unroll
  for (int dt = 0; dt < 2; ++dt) {
    float su = ssum[dt], sq = ssq[dt];
    su += __shfl_xor(su, 16); sq += __shfl_xor(sq, 16);
    su += __shfl_xor(su, 32); sq += __shfl_xor(sq, 32);
    if (lhi == 0) {
      const int col = h * 32 + dt * 16 + l16;
      atomicAdd(&stats[col], su);
      atomicAdd(&stats[512 + col], sq);
    }
  }
}

// ---------------- BatchNorm finalize + apply ----------------
__global__ void k_bn_fin(float* __restrict__ S, const float* __restrict__ g,
                         const float* __restrict__ be, float* __restrict__ coef) {
  const int d = threadIdx.x;
  const float inv = 1.0f / 8192.0f;
  const float mean = S[d] * inv;
  const float var = S[512 + d] * inv - mean * mean;
  const float a = rsqrtf(var + 1e-5f) * g[d];
  coef[d] = a;
  coef[512 + d] = be[d] - mean * a;
  S[d] = 0.f; S[512 + d] = 0.f;
}

__global__ __launch_bounds__(256) void k_bn_applyB(const float* __restrict__ X, const float* __restrict__ coef,
                                                   u16* __restrict__ Yb) {
  const int n4 = NROW * DD / 4;
  for (int i = blockIdx.x * 256 + threadIdx.x; i < n4; i += gridDim.x * 256) {
    const float4 xv = ((const float4*)X)[i];
    const int d = (i & 127) * 4;
    u16x4v o;
    o[0] = f2b(fmaf(xv.x, coef[d + 0], coef[512 + d + 0]));
    o[1] = f2b(fmaf(xv.y, coef[d + 1], coef[512 + d + 1]));
    o[2] = f2b(fmaf(xv.z, coef[d + 2], coef[512 + d + 2]));
    o[3] = f2b(fmaf(xv.w, coef[d + 3], coef[512 + d + 3]));
    ((u16x4v*)Yb)[i] = o;
  }
}

__global__ __launch_bounds__(256) void k_bn_applyF(const float* __restrict__ X, const float* __restrict__ coef,
                                                   float* __restrict__ Yf) {
  const int n4 = NROW * DD / 4;
  for (int i = blockIdx.x * 256 + threadIdx.x; i < n4; i += gridDim.x * 256) {
    const float4 xv = ((const float4*)X)[i];
    const int d = (i & 127) * 4;
    float4 o;
    o.x = fmaf(xv.x, coef[d + 0], coef[512 + d + 0]);
    o.y = fmaf(xv.y, coef[d + 1], coef[512 + d + 1]);
    o.z = fmaf(xv.z, coef[d + 2], coef[512 + d + 2]);
    o.w = fmaf(xv.w, coef[d + 3], coef[512 + d + 3]);
    ((float4*)Yf)[i] = o;
  }
}

// ---------------- host launch ----------------
extern "C" void kernel_launch(void* const* d_in, const int* in_sizes, int n_in,
                              void* d_out, int out_size, void* d_ws, size_t ws_size,
                              hipStream_t stream) {
  const float* x    = (const float*)d_in[0];
  const float* emb  = (const float*)d_in[1];
  const float* bn2g = (const float*)d_in[2];
  const float* bn2b = (const float*)d_in[3];
  const float* Wq   = (const float*)d_in[4];
  const float* bq   = (const float*)d_in[5];
  const float* Wk   = (const float*)d_in[6];
  const float* bkp  = (const float*)d_in[7];
  const float* Wv   = (const float*)d_in[8];
  const float* bvp  = (const float*)d_in[9];
  const float* bnag = (const float*)d_in[10];
  const float* bnab = (const float*)d_in[11];
  const float* W1   = (const float*)d_in[12];
  const float* b1   = (const float*)d_in[13];
  const float* W2   = (const float*)d_in[14];
  const float* b2   = (const float*)d_in[15];
  const float* bnfg = (const float*)d_in[16];
  const float* bnfb = (const float*)d_in[17];

  char* p = (char*)d_ws;
  auto alloc = [&](size_t bytes) { char* r = p; p += (bytes + 255) & ~(size_t)255; return r; };
  u16*   xb    = (u16*)alloc((size_t)NROW * DD * 2);
  u16*   encB  = (u16*)alloc((size_t)NROW * DD * 2);
  float* tF    = (float*)alloc((size_t)NROW * DD * 4);
  u16*   qkv   = (u16*)alloc((size_t)3 * NROW * DD * 2); // Q | K | V
  u16*   h1    = (u16*)alloc((size_t)NROW * FF_ * 2);
  float* Z     = (float*)alloc((size_t)LL * LL * 4);
  float* sums  = (float*)alloc(1024 * 4);
  float* coef  = (float*)alloc(1024 * 4);
  float* bqkv  = (float*)alloc(1536 * 4);
  u16*   embT  = (u16*)alloc((size_t)DD * DD * 2);
  u16*   wqkvT = (u16*)alloc((size_t)3 * DD * DD * 2);
  u16*   w1T   = (u16*)alloc((size_t)DD * FF_ * 2);
  u16*   w2T   = (u16*)alloc((size_t)FF_ * DD * 2);
  if ((size_t)(p - (char*)d_ws) > ws_size) return;

  k_zero<<<4, 256, 0, stream>>>(sums, 1024);
  k_f32_to_bf16<<<2048, 256, 0, stream>>>(x, xb, NROW * DD / 4);
  k_wtrans<<<dim3(16, 16), 256, 0, stream>>>(emb, embT, DD, DD);
  k_gemm<64, 1, 0, 0, 0, 0, 1, 0, 1, 0><<<dim3(128, 4), 256, 0, stream>>>(
      xb, embT, nullptr, nullptr, nullptr, tF, nullptr, sums, DD, DD);
  k_bn_fin<<<1, 512, 0, stream>>>(sums, bn2g, bn2b, coef);
  k_bn_applyB<<<2048, 256, 0, stream>>>(tF, coef, encB);

  for (int i = 0; i < 3; ++i) {
    k_wtrans<<<dim3(16, 16), 256, 0, stream>>>(Wq + (size_t)i * DD * DD, wqkvT, DD, DD);
    k_wtrans<<<dim3(16, 16), 256, 0, stream>>>(Wk + (size_t)i * DD * DD, wqkvT + (size_t)512 * DD, DD, DD);
    k_wtrans<<<dim3(16, 16), 256, 0, stream>>>(Wv + (size_t)i * DD * DD, wqkvT + (size_t)1024 * DD, DD, DD);
    k_catbias<<<6, 256, 0, stream>>>(bq + i * DD, bkp + i * DD, bvp + i * DD, bqkv);
    k_gemm<128, 0, 1, 1, 0, 0, 0, 1, 0, 1><<<dim3(64, 12), 256, 0, stream>>>(
        encB, wqkvT, bqkv, nullptr, nullptr, nullptr, qkv, nullptr, DD, 1536);
    k_zero<<<1024, 256, 0, stream>>>(Z, LL * LL);
    k_attn_z<<<dim3(8, 8, 16), 256, 0, stream>>>(qkv, qkv + QKVOFF, Z);
    k_recip<<<1024, 256, 0, stream>>>(Z, LL * LL);
    k_attn_pv3<<<256, 1024, 0, stream>>>(qkv, qkv + QKVOFF, qkv + 2 * QKVOFF, Z, coef, tF, sums);
    k_bn_fin<<<1, 512, 0, stream>>>(sums, bnag + i * DD, bnab + i * DD, coef);
    k_bn_applyB<<<2048, 256, 0, stream>>>(tF, coef, encB);
    k_wtrans<<<dim3(16, 64), 256, 0, stream>>>(W1 + (size_t)i * DD * FF_, w1T, DD, FF_);
    k_gemm<128, 0, 1, 1, 0, 0, 0, 1, 0, 0><<<dim3(64, 16), 256, 0, stream>>>(
        encB, w1T, b1 + i * FF_, nullptr, nullptr, nullptr, h1, nullptr, DD, FF_);
    k_wtrans<<<dim3(64, 16), 256, 0, stream>>>(W2 + (size_t)i * FF_ * DD, w2T, FF_, DD);
    k_gemm<64, 1, 0, 1, 1, 1, 1, 0, 1, 0><<<dim3(128, 4), 256, 0, stream>>>(
        h1, w2T, b2 + i * DD, tF, coef, tF, nullptr, sums, FF_, DD);
    k_bn_fin<<<1, 512, 0, stream>>>(sums, bnfg + i * DD, bnfb + i * DD, coef);
    if (i == 2) k_bn_applyF<<<2048, 256, 0, stream>>>(tF, coef, (float*)d_out);
    else        k_bn_applyB<<<2048, 256, 0, stream>>>(tF, coef, encB);
  }
}

// Round 14
// 618.253 us; speedup vs baseline: 1.0694x; 1.0694x over previous
//
#include <hip/hip_runtime.h>

#define DEVI __device__ __forceinline__

typedef unsigned short u16;
typedef unsigned int u32;
typedef __attribute__((ext_vector_type(8))) short s16x8;
typedef __attribute__((ext_vector_type(4))) float f32x4;
typedef __attribute__((ext_vector_type(4))) unsigned short u16x4v;
typedef __attribute__((ext_vector_type(2))) unsigned int u32x2;

constexpr int NB   = 16;
constexpr int LL   = 512;
constexpr int DD   = 512;
constexpr int FF_  = 2048;
constexpr int NROW = NB * LL;                  // 8192
constexpr float C2 = 0.17677669529663687f * 1.4426950408889634f; // scale*log2(e)
constexpr size_t QKVOFF = (size_t)NROW * DD;   // elems per Q/K/V segment

DEVI u16 f2b(float f) {
  unsigned int u = __float_as_uint(f);
  unsigned int r = u + 0x7FFFu + ((u >> 16) & 1u); // RNE
  return (u16)(r >> 16);
}

// async global->LDS, 16B per lane; LDS dest = uniform base + lane*16
DEVI void gload16(const void* g, void* l) {
  __builtin_amdgcn_global_load_lds(
      (const __attribute__((address_space(1))) unsigned int*)(unsigned long long)g,
      (__attribute__((address_space(3))) unsigned int*)(unsigned int)(unsigned long long)l,
      16, 0, 0);
}

// ---------------- elementwise helpers ----------------
__global__ __launch_bounds__(256) void k_f32_to_bf16(const float* __restrict__ X, u16* __restrict__ Y, int n4) {
  for (int i = blockIdx.x * 256 + threadIdx.x; i < n4; i += gridDim.x * 256) {
    float4 x = ((const float4*)X)[i];
    u16x4v o; o[0] = f2b(x.x); o[1] = f2b(x.y); o[2] = f2b(x.z); o[3] = f2b(x.w);
    ((u16x4v*)Y)[i] = o;
  }
}

__global__ __launch_bounds__(256) void k_zero(float* __restrict__ p, int n) {
  int i = blockIdx.x * 256 + threadIdx.x;
  if (i < n) p[i] = 0.f;
}

__global__ __launch_bounds__(256) void k_recip(float* __restrict__ p, int n) {
  int i = blockIdx.x * 256 + threadIdx.x;
  if (i < n) p[i] = 1.0f / p[i];
}

__global__ void k_catbias(const float* __restrict__ a, const float* __restrict__ b,
                          const float* __restrict__ c, float* __restrict__ o) {
  int i = blockIdx.x * 256 + threadIdx.x; // 1536
  o[i] = (i < 512) ? a[i] : (i < 1024) ? b[i - 512] : c[i - 1024];
}

// ---------------- weight transpose + convert: WT[m*K+k] = bf16(W[k*M+m]) ----------------
__global__ __launch_bounds__(256) void k_wtrans(const float* __restrict__ W, u16* __restrict__ WT, int K, int M) {
  __shared__ float tile[32][33];
  const int k0 = blockIdx.x * 32, m0 = blockIdx.y * 32;
  const int tx = threadIdx.x & 31, ty = threadIdx.x >> 5;
#pragma unroll
  for (int j = 0; j < 4; ++j) tile[ty + j * 8][tx] = W[(size_t)(k0 + ty + j * 8) * M + m0 + tx];
  __syncthreads();
#pragma unroll
  for (int j = 0; j < 4; ++j) WT[(size_t)(m0 + ty + j * 8) * K + k0 + tx] = f2b(tile[tx][ty + j * 8]);
}

// ---------------- GEMM: C = act(A.Bt + bias) [+ BN(Res)] ----------------
// DBUF=1: 2-phase double-buffered pipeline (proven +1.6x on BM=64 in R11).
template <int BM, int DBUF, int RELU, int HASB, int HASRES, int RESBN, int OUTF, int OUTB, int STATS, int SPLIT3>
__global__ __launch_bounds__(256) void k_gemm(const u16* __restrict__ A, const u16* __restrict__ Bt,
                                              const float* __restrict__ bias, const float* Res,
                                              const float* __restrict__ resco,
                                              float* Cf, u16* __restrict__ Cb,
                                              float* __restrict__ stats, int K, int Ncols) {
  constexpr int WR = BM / 64;
  constexpr int WC = 4 / WR;
  constexpr int MW = 4;
  constexpr int NW = 128 / (16 * WC);
  __shared__ __align__(16) u16 As[(DBUF ? 2 : 1) * BM * 64];
  __shared__ __align__(16) u16 Bs[(DBUF ? 2 : 1) * 128 * 64];
  const int t = threadIdx.x, lane = t & 63, w = t >> 6;
  const int wr = w / WC, wc = w % WC, l16 = lane & 15, lhi = lane >> 4;
  const int row0 = blockIdx.x * BM, col0 = blockIdx.y * 128;
  const int sr = lane >> 3, sc = (lane & 7) * 8;
  const u16* Ag = A + (size_t)(row0 + sr) * K + sc;
  const u16* Bg = Bt + (size_t)(col0 + sr) * K + sc;

  f32x4 acc[MW][NW] = {};

  auto stage = [&](int buf, int k0) {
    u16* Ad = As + buf * (BM * 64);
    u16* Bd = Bs + buf * (128 * 64);
#pragma unroll
    for (int j = 0; j < BM / 32; ++j) {
      const int ch = w * (BM / 32) + j;
      gload16(Ag + (size_t)(ch * 8) * K + k0, Ad + ch * 512);
    }
#pragma unroll
    for (int j = 0; j < 4; ++j) {
      const int ch = w * 4 + j;
      gload16(Bg + (size_t)(ch * 8) * K + k0, Bd + ch * 512);
    }
  };

  auto compute = [&](const u16* Ab, const u16* Bb) {
#pragma unroll
    for (int kk = 0; kk < 2; ++kk) {
      s16x8 af[MW], bfv[NW];
#pragma unroll
      for (int m = 0; m < MW; ++m) af[m] = *(const s16x8*)(Ab + (wr * 64 + m * 16 + l16) * 64 + kk * 32 + lhi * 8);
#pragma unroll
      for (int n = 0; n < NW; ++n) bfv[n] = *(const s16x8*)(Bb + (wc * (16 * NW) + n * 16 + l16) * 64 + kk * 32 + lhi * 8);
#pragma unroll
      for (int m = 0; m < MW; ++m)
#pragma unroll
        for (int n = 0; n < NW; ++n)
          acc[m][n] = __builtin_amdgcn_mfma_f32_16x16x32_bf16(af[m], bfv[n], acc[m][n], 0, 0, 0);
    }
  };

  if constexpr (DBUF) {
    stage(0, 0);
    const int NT = K >> 6;
    for (int kt = 0; kt < NT; ++kt) {
      const int cur = kt & 1;
      __syncthreads();
      if (kt + 1 < NT) stage(cur ^ 1, (kt + 1) << 6);
      compute(As + cur * (BM * 64), Bs + cur * (128 * 64));
    }
  } else {
    for (int k0 = 0; k0 < K; k0 += 64) {
      __syncthreads();
      stage(0, k0);
      __syncthreads();
      compute(As, Bs);
    }
  }

#pragma unroll
  for (int n = 0; n < NW; ++n) {
    const int col = col0 + wc * (16 * NW) + n * 16 + l16;
    float bv = 0.f;
    if constexpr (HASB) bv = bias[col];
    float ra = 0.f, rc = 0.f;
    if constexpr (RESBN) { ra = resco[col]; rc = resco[512 + col]; }
    float ssum = 0.f, ssq = 0.f;
#pragma unroll
    for (int m = 0; m < MW; ++m) {
      const int rbase = row0 + wr * 64 + m * 16 + lhi * 4;
#pragma unroll
      for (int r = 0; r < 4; ++r) {
        float v = acc[m][n][r] + bv;
        if constexpr (RELU) v = fmaxf(v, 0.f);
        const int row = rbase + r;
        const size_t idx = (size_t)row * Ncols + col;
        if constexpr (HASRES) {
          if constexpr (RESBN) v += fmaf(Res[idx], ra, rc);
          else v += Res[idx];
        }
        if constexpr (OUTF) Cf[idx] = v;
        if constexpr (OUTB) {
          if constexpr (SPLIT3) {
            const size_t ib = (size_t)(col >> 9) * QKVOFF + (size_t)row * DD + (col & 511);
            Cb[ib] = f2b(v);
          } else {
            Cb[idx] = f2b(v);
          }
        }
        if constexpr (STATS) { ssum += v; ssq += v * v; }
      }
    }
    if constexpr (STATS) {
      ssum += __shfl_xor(ssum, 16); ssq += __shfl_xor(ssq, 16);
      ssum += __shfl_xor(ssum, 32); ssq += __shfl_xor(ssq, 32);
      if (lhi == 0) {
        atomicAdd(&stats[col], ssum);
        atomicAdd(&stats[512 + col], ssq);
      }
    }
  }
}

// ---------------- attention pass 1: Z[q,k] = sum_n exp(scale * Q_[n,q,:].K_[n,k,:]) ----------------
__global__ __launch_bounds__(256) void k_attn_z(const u16* __restrict__ Q, const u16* __restrict__ Kt,
                                                float* __restrict__ Z) {
  const int t = threadIdx.x, lane = t & 63, w = t >> 6;
  const int l16 = lane & 15, lhi = lane >> 4;
  const int q0 = blockIdx.x * 64 + (w >> 1) * 32;
  const int k0 = blockIdx.y * 64 + (w & 1) * 32;
  const int n0 = blockIdx.z * 16;
  f32x4 zac[2][2] = {};
  for (int nn = 0; nn < 16; ++nn) {
    const int n = n0 + nn, h = n >> 4, b = n & 15;
    const size_t base = (size_t)b * LL * DD + (size_t)h * 32;
    s16x8 a[2], bb[2];
#pragma unroll
    for (int mi = 0; mi < 2; ++mi) a[mi] = *(const s16x8*)(Q + base + (size_t)(q0 + mi * 16 + l16) * DD + lhi * 8);
#pragma unroll
    for (int ni = 0; ni < 2; ++ni) bb[ni] = *(const s16x8*)(Kt + base + (size_t)(k0 + ni * 16 + l16) * DD + lhi * 8);
#pragma unroll
    for (int mi = 0; mi < 2; ++mi)
#pragma unroll
      for (int ni = 0; ni < 2; ++ni) {
        f32x4 z4 = {0.f, 0.f, 0.f, 0.f};
        f32x4 s = __builtin_amdgcn_mfma_f32_16x16x32_bf16(a[mi], bb[ni], z4, 0, 0, 0);
#pragma unroll
        for (int r = 0; r < 4; ++r) zac[mi][ni][r] += exp2f(s[r] * C2);
      }
  }
#pragma unroll
  for (int mi = 0; mi < 2; ++mi)
#pragma unroll
    for (int ni = 0; ni < 2; ++ni)
#pragma unroll
      for (int r = 0; r < 4; ++r)
        atomicAdd(&Z[(q0 + mi * 16 + lhi * 4 + r) * LL + k0 + ni * 16 + l16], zac[mi][ni][r]);
}

// ---------------- attention pass 2 (pv3, R12 version): K/V LDS-resident, per-wave P LDS buffer ----------------
__global__ __launch_bounds__(1024) void k_attn_pv3(const u16* __restrict__ Q, const u16* __restrict__ K,
                                                   const u16* __restrict__ V, const float* __restrict__ IZ,
                                                   const float* __restrict__ resco, float* T,
                                                   float* __restrict__ stats) {
  __shared__ __align__(16) u16 Kl[512 * 40];   // rows padded 32->40 u16
  __shared__ __align__(16) u16 Vl[32 * 520];   // d-major rows padded 512->520 u16
  __shared__ __align__(16) u16 Pl[16][1024];   // per-wave P transpose buffer
  const int n = blockIdx.x, h = n >> 4, b = n & 15;
  const int t = threadIdx.x, lane = t & 63, w = t >> 6;
  const int l16 = lane & 15, lhi = lane >> 4;
  const size_t base = (size_t)b * LL * DD + (size_t)h * 32;

  // stage K: 2048 x 16B chunks (2 per thread)
#pragma unroll
  for (int j = 0; j < 2; ++j) {
    const int c = t + j * 1024;
    const int k = c >> 2, part = c & 3;
    const s16x8 v = *(const s16x8*)(K + base + (size_t)k * DD + part * 8);
    *(s16x8*)(Kl + k * 40 + part * 8) = v;
  }
  // stage V with in-flight transpose
#pragma unroll
  for (int j = 0; j < 2; ++j) {
    const int c = t + j * 1024;
    const int k = c >> 2, dp = c & 3;
    const s16x8 v = *(const s16x8*)(V + base + (size_t)k * DD + dp * 8);
#pragma unroll
    for (int jj = 0; jj < 8; ++jj) Vl[(dp * 8 + jj) * 520 + k] = (u16)v[jj];
  }
  // preload this wave's 2 Q fragments
  const int qbase = w * 32;
  s16x8 aqv[2];
#pragma unroll
  for (int qf = 0; qf < 2; ++qf)
    aqv[qf] = *(const s16x8*)(Q + base + (size_t)(qbase + qf * 16 + l16) * DD + lhi * 8);
  float ra[2], rc[2];
#pragma unroll
  for (int dt = 0; dt < 2; ++dt) {
    const int col = h * 32 + dt * 16 + l16;
    ra[dt] = resco[col]; rc[dt] = resco[512 + col];
  }
  __syncthreads();

  char* P = (char*)&Pl[w][0];
  const int wxor = (l16 & 7) << 4;
  const int wbase = l16 * 128 + lhi * 8;
  float ssum[2] = {0.f, 0.f}, ssq[2] = {0.f, 0.f};

#pragma unroll
  for (int qf = 0; qf < 2; ++qf) {
    const int q16 = qbase + qf * 16;
    const float* izrow = IZ + (size_t)(q16 + l16) * LL + lhi * 4;
    f32x4 oa[2] = {};
#pragma unroll
    for (int kt = 0; kt < 8; ++kt) {
      const int kb = kt * 64;
      f32x4 s[4]; float4 iz[4];
#pragma unroll
      for (int ks = 0; ks < 4; ++ks) {
        const s16x8 af = *(const s16x8*)(Kl + (kb + ks * 16 + l16) * 40 + lhi * 8);
        f32x4 z4 = {0.f, 0.f, 0.f, 0.f};
        s[ks] = __builtin_amdgcn_mfma_f32_16x16x32_bf16(af, aqv[qf], z4, 0, 0, 0);
        iz[ks] = *(const float4*)(izrow + kb + ks * 16);
      }
#pragma unroll
      for (int ks = 0; ks < 4; ++ks) {
        const float p0 = exp2f(s[ks][0] * C2) * iz[ks].x;
        const float p1 = exp2f(s[ks][1] * C2) * iz[ks].y;
        const float p2 = exp2f(s[ks][2] * C2) * iz[ks].z;
        const float p3 = exp2f(s[ks][3] * C2) * iz[ks].w;
        unsigned int pk0, pk1;
        asm("v_cvt_pk_bf16_f32 %0, %1, %2" : "=v"(pk0) : "v"(p0), "v"(p1));
        asm("v_cvt_pk_bf16_f32 %0, %1, %2" : "=v"(pk1) : "v"(p2), "v"(p3));
        u32x2 pw; pw[0] = pk0; pw[1] = pk1;
        *(u32x2*)(P + ((wbase + ks * 32) ^ wxor)) = pw;
      }
#pragma unroll
      for (int kc = 0; kc < 2; ++kc) {
        const s16x8 pa = *(const s16x8*)(P + ((l16 * 128 + kc * 64 + lhi * 16) ^ wxor));
#pragma unroll
        for (int dt = 0; dt < 2; ++dt) {
          const s16x8 bv = *(const s16x8*)(Vl + (dt * 16 + l16) * 520 + kb + kc * 32 + lhi * 8);
          oa[dt] = __builtin_amdgcn_mfma_f32_16x16x32_bf16(pa, bv, oa[dt], 0, 0, 0);
        }
      }
    }
#pragma unroll
    for (int dt = 0; dt < 2; ++dt)
#pragma unroll
      for (int r = 0; r < 4; ++r) {
        const size_t idx = (size_t)(b * LL + q16 + lhi * 4 + r) * DD + h * 32 + dt * 16 + l16;
        const float v = oa[dt][r] + fmaf(T[idx], ra[dt], rc[dt]);
        T[idx] = v;
        ssum[dt] += v; ssq[dt] += v * v;
      }
  }
#pragma unroll
  for (int dt = 0; dt < 2; ++dt) {
    float su = ssum[dt], sq = ssq[dt];
    su += __shfl_xor(su, 16); sq += __shfl_xor(sq, 16);
    su += __shfl_xor(su, 32); sq += __shfl_xor(sq, 32);
    if (lhi == 0) {
      const int col = h * 32 + dt * 16 + l16;
      atomicAdd(&stats[col], su);
      atomicAdd(&stats[512 + col], sq);
    }
  }
}

// ---------------- BatchNorm finalize + apply ----------------
__global__ void k_bn_fin(float* __restrict__ S, const float* __restrict__ g,
                         const float* __restrict__ be, float* __restrict__ coef) {
  const int d = threadIdx.x;
  const float inv = 1.0f / 8192.0f;
  const float mean = S[d] * inv;
  const float var = S[512 + d] * inv - mean * mean;
  const float a = rsqrtf(var + 1e-5f) * g[d];
  coef[d] = a;
  coef[512 + d] = be[d] - mean * a;
  S[d] = 0.f; S[512 + d] = 0.f;
}

__global__ __launch_bounds__(256) void k_bn_applyB(const float* __restrict__ X, const float* __restrict__ coef,
                                                   u16* __restrict__ Yb) {
  const int n4 = NROW * DD / 4;
  for (int i = blockIdx.x * 256 + threadIdx.x; i < n4; i += gridDim.x * 256) {
    const float4 xv = ((const float4*)X)[i];
    const int d = (i & 127) * 4;
    u16x4v o;
    o[0] = f2b(fmaf(xv.x, coef[d + 0], coef[512 + d + 0]));
    o[1] = f2b(fmaf(xv.y, coef[d + 1], coef[512 + d + 1]));
    o[2] = f2b(fmaf(xv.z, coef[d + 2], coef[512 + d + 2]));
    o[3] = f2b(fmaf(xv.w, coef[d + 3], coef[512 + d + 3]));
    ((u16x4v*)Yb)[i] = o;
  }
}

__global__ __launch_bounds__(256) void k_bn_applyF(const float* __restrict__ X, const float* __restrict__ coef,
                                                   float* __restrict__ Yf) {
  const int n4 = NROW * DD / 4;
  for (int i = blockIdx.x * 256 + threadIdx.x; i < n4; i += gridDim.x * 256) {
    const float4 xv = ((const float4*)X)[i];
    const int d = (i & 127) * 4;
    float4 o;
    o.x = fmaf(xv.x, coef[d + 0], coef[512 + d + 0]);
    o.y = fmaf(xv.y, coef[d + 1], coef[512 + d + 1]);
    o.z = fmaf(xv.z, coef[d + 2], coef[512 + d + 2]);
    o.w = fmaf(xv.w, coef[d + 3], coef[512 + d + 3]);
    ((float4*)Yf)[i] = o;
  }
}

// ---------------- host launch ----------------
extern "C" void kernel_launch(void* const* d_in, const int* in_sizes, int n_in,
                              void* d_out, int out_size, void* d_ws, size_t ws_size,
                              hipStream_t stream) {
  const float* x    = (const float*)d_in[0];
  const float* emb  = (const float*)d_in[1];
  const float* bn2g = (const float*)d_in[2];
  const float* bn2b = (const float*)d_in[3];
  const float* Wq   = (const float*)d_in[4];
  const float* bq   = (const float*)d_in[5];
  const float* Wk   = (const float*)d_in[6];
  const float* bkp  = (const float*)d_in[7];
  const float* Wv   = (const float*)d_in[8];
  const float* bvp  = (const float*)d_in[9];
  const float* bnag = (const float*)d_in[10];
  const float* bnab = (const float*)d_in[11];
  const float* W1   = (const float*)d_in[12];
  const float* b1   = (const float*)d_in[13];
  const float* W2   = (const float*)d_in[14];
  const float* b2   = (const float*)d_in[15];
  const float* bnfg = (const float*)d_in[16];
  const float* bnfb = (const float*)d_in[17];

  char* p = (char*)d_ws;
  auto alloc = [&](size_t bytes) { char* r = p; p += (bytes + 255) & ~(size_t)255; return r; };
  u16*   xb    = (u16*)alloc((size_t)NROW * DD * 2);
  u16*   encB  = (u16*)alloc((size_t)NROW * DD * 2);
  float* tF    = (float*)alloc((size_t)NROW * DD * 4);
  u16*   qkv   = (u16*)alloc((size_t)3 * NROW * DD * 2); // Q | K | V
  u16*   h1    = (u16*)alloc((size_t)NROW * FF_ * 2);
  float* Z     = (float*)alloc((size_t)LL * LL * 4);
  float* sums  = (float*)alloc(1024 * 4);
  float* coef  = (float*)alloc(1024 * 4);
  float* bqkv  = (float*)alloc(1536 * 4);
  u16*   embT  = (u16*)alloc((size_t)DD * DD * 2);
  u16*   wqkvT = (u16*)alloc((size_t)3 * DD * DD * 2);
  u16*   w1T   = (u16*)alloc((size_t)DD * FF_ * 2);
  u16*   w2T   = (u16*)alloc((size_t)FF_ * DD * 2);
  if ((size_t)(p - (char*)d_ws) > ws_size) return;

  k_zero<<<4, 256, 0, stream>>>(sums, 1024);
  k_f32_to_bf16<<<2048, 256, 0, stream>>>(x, xb, NROW * DD / 4);
  k_wtrans<<<dim3(16, 16), 256, 0, stream>>>(emb, embT, DD, DD);
  k_gemm<64, 1, 0, 0, 0, 0, 1, 0, 1, 0><<<dim3(128, 4), 256, 0, stream>>>(
      xb, embT, nullptr, nullptr, nullptr, tF, nullptr, sums, DD, DD);
  k_bn_fin<<<1, 512, 0, stream>>>(sums, bn2g, bn2b, coef);
  k_bn_applyB<<<2048, 256, 0, stream>>>(tF, coef, encB);

  for (int i = 0; i < 3; ++i) {
    k_wtrans<<<dim3(16, 16), 256, 0, stream>>>(Wq + (size_t)i * DD * DD, wqkvT, DD, DD);
    k_wtrans<<<dim3(16, 16), 256, 0, stream>>>(Wk + (size_t)i * DD * DD, wqkvT + (size_t)512 * DD, DD, DD);
    k_wtrans<<<dim3(16, 16), 256, 0, stream>>>(Wv + (size_t)i * DD * DD, wqkvT + (size_t)1024 * DD, DD, DD);
    k_catbias<<<6, 256, 0, stream>>>(bq + i * DD, bkp + i * DD, bvp + i * DD, bqkv);
    // QKV GEMM: BM=128, double-buffered (64KB LDS, 2 blocks/CU)
    k_gemm<128, 1, 1, 1, 0, 0, 0, 1, 0, 1><<<dim3(64, 12), 256, 0, stream>>>(
        encB, wqkvT, bqkv, nullptr, nullptr, nullptr, qkv, nullptr, DD, 1536);
    k_zero<<<1024, 256, 0, stream>>>(Z, LL * LL);
    k_attn_z<<<dim3(8, 8, 16), 256, 0, stream>>>(qkv, qkv + QKVOFF, Z);
    k_recip<<<1024, 256, 0, stream>>>(Z, LL * LL);
    k_attn_pv3<<<256, 1024, 0, stream>>>(qkv, qkv + QKVOFF, qkv + 2 * QKVOFF, Z, coef, tF, sums);
    k_bn_fin<<<1, 512, 0, stream>>>(sums, bnag + i * DD, bnab + i * DD, coef);
    k_bn_applyB<<<2048, 256, 0, stream>>>(tF, coef, encB);
    k_wtrans<<<dim3(16, 64), 256, 0, stream>>>(W1 + (size_t)i * DD * FF_, w1T, DD, FF_);
    // FF1: BM=128, double-buffered
    k_gemm<128, 1, 1, 1, 0, 0, 0, 1, 0, 0><<<dim3(64, 16), 256, 0, stream>>>(
        encB, w1T, b1 + i * FF_, nullptr, nullptr, nullptr, h1, nullptr, DD, FF_);
    k_wtrans<<<dim3(64, 16), 256, 0, stream>>>(W2 + (size_t)i * FF_ * DD, w2T, FF_, DD);
    k_gemm<64, 1, 0, 1, 1, 1, 1, 0, 1, 0><<<dim3(128, 4), 256, 0, stream>>>(
        h1, w2T, b2 + i * DD, tF, coef, tF, nullptr, sums, FF_, DD);
    k_bn_fin<<<1, 512, 0, stream>>>(sums, bnfg + i * DD, bnfb + i * DD, coef);
    if (i == 2) k_bn_applyF<<<2048, 256, 0, stream>>>(tF, coef, (float*)d_out);
    else        k_bn_applyB<<<2048, 256, 0, stream>>>(tF, coef, encB);
  }
}

// Round 15
// 608.744 us; speedup vs baseline: 1.0861x; 1.0156x over previous
//
#include <hip/hip_runtime.h>

#define DEVI __device__ __forceinline__

typedef unsigned short u16;
typedef unsigned int u32;
typedef __attribute__((ext_vector_type(8))) short s16x8;
typedef __attribute__((ext_vector_type(4))) float f32x4;
typedef __attribute__((ext_vector_type(4))) unsigned short u16x4v;
typedef __attribute__((ext_vector_type(2))) unsigned int u32x2;

constexpr int NB   = 16;
constexpr int LL   = 512;
constexpr int DD   = 512;
constexpr int FF_  = 2048;
constexpr int NROW = NB * LL;                  // 8192
constexpr float C2 = 0.17677669529663687f * 1.4426950408889634f; // scale*log2(e)
constexpr size_t QKVOFF = (size_t)NROW * DD;   // elems per Q/K/V segment

DEVI u16 f2b(float f) {
  unsigned int u = __float_as_uint(f);
  unsigned int r = u + 0x7FFFu + ((u >> 16) & 1u); // RNE
  return (u16)(r >> 16);
}

// derive BN coef (a, c) for one column from raw sums
DEVI void bn_coef2(const float* __restrict__ S, const float* __restrict__ g,
                   const float* __restrict__ be, int col, float& a, float& c) {
  const float inv = 1.0f / 8192.0f;
  const float mean = S[col] * inv;
  const float var = S[512 + col] * inv - mean * mean;
  a = rsqrtf(var + 1e-5f) * g[col];
  c = be[col] - mean * a;
}

// async global->LDS, 16B per lane; LDS dest = uniform base + lane*16
DEVI void gload16(const void* g, void* l) {
  __builtin_amdgcn_global_load_lds(
      (const __attribute__((address_space(1))) unsigned int*)(unsigned long long)g,
      (__attribute__((address_space(3))) unsigned int*)(unsigned int)(unsigned long long)l,
      16, 0, 0);
}

// ---------------- elementwise helpers ----------------
__global__ __launch_bounds__(256) void k_f32_to_bf16(const float* __restrict__ X, u16* __restrict__ Y, int n4) {
  for (int i = blockIdx.x * 256 + threadIdx.x; i < n4; i += gridDim.x * 256) {
    float4 x = ((const float4*)X)[i];
    u16x4v o; o[0] = f2b(x.x); o[1] = f2b(x.y); o[2] = f2b(x.z); o[3] = f2b(x.w);
    ((u16x4v*)Y)[i] = o;
  }
}

__global__ __launch_bounds__(256) void k_zero(float* __restrict__ p, int n) {
  int i = blockIdx.x * 256 + threadIdx.x;
  if (i < n) p[i] = 0.f;
}

__global__ __launch_bounds__(256) void k_recip(float* __restrict__ p, int n) {
  int i = blockIdx.x * 256 + threadIdx.x;
  if (i < n) p[i] = 1.0f / p[i];
}

__global__ void k_catbias(const float* __restrict__ a, const float* __restrict__ b,
                          const float* __restrict__ c, float* __restrict__ o) {
  int i = blockIdx.x * 256 + threadIdx.x; // 1536
  o[i] = (i < 512) ? a[i] : (i < 1024) ? b[i - 512] : c[i - 1024];
}

// ---------------- weight transpose + convert: WT[m*K+k] = bf16(W[k*M+m]) ----------------
__global__ __launch_bounds__(256) void k_wtrans(const float* __restrict__ W, u16* __restrict__ WT, int K, int M) {
  __shared__ float tile[32][33];
  const int k0 = blockIdx.x * 32, m0 = blockIdx.y * 32;
  const int tx = threadIdx.x & 31, ty = threadIdx.x >> 5;
#pragma unroll
  for (int j = 0; j < 4; ++j) tile[ty + j * 8][tx] = W[(size_t)(k0 + ty + j * 8) * M + m0 + tx];
  __syncthreads();
#pragma unroll
  for (int j = 0; j < 4; ++j) WT[(size_t)(m0 + ty + j * 8) * K + k0 + tx] = f2b(tile[tx][ty + j * 8]);
}

// ---------------- GEMM: C = act(A.Bt + bias) [+ BN(Res)] ----------------
// DBUF=1: 2-phase double-buffered pipeline.
// RESBN: residual = Res[idx]*a[col]+c[col], coefs derived in-epilogue from (resS,resg,resb).
template <int BM, int DBUF, int RELU, int HASB, int HASRES, int RESBN, int OUTF, int OUTB, int STATS, int SPLIT3>
__global__ __launch_bounds__(256) void k_gemm(const u16* __restrict__ A, const u16* __restrict__ Bt,
                                              const float* __restrict__ bias, const float* Res,
                                              const float* __restrict__ resS, const float* __restrict__ resg,
                                              const float* __restrict__ resb,
                                              float* Cf, u16* __restrict__ Cb,
                                              float* __restrict__ stats, int K, int Ncols) {
  constexpr int WR = BM / 64;
  constexpr int WC = 4 / WR;
  constexpr int MW = 4;
  constexpr int NW = 128 / (16 * WC);
  __shared__ __align__(16) u16 As[(DBUF ? 2 : 1) * BM * 64];
  __shared__ __align__(16) u16 Bs[(DBUF ? 2 : 1) * 128 * 64];
  const int t = threadIdx.x, lane = t & 63, w = t >> 6;
  const int wr = w / WC, wc = w % WC, l16 = lane & 15, lhi = lane >> 4;
  const int row0 = blockIdx.x * BM, col0 = blockIdx.y * 128;
  const int sr = lane >> 3, sc = (lane & 7) * 8;
  const u16* Ag = A + (size_t)(row0 + sr) * K + sc;
  const u16* Bg = Bt + (size_t)(col0 + sr) * K + sc;

  f32x4 acc[MW][NW] = {};

  auto stage = [&](int buf, int k0) {
    u16* Ad = As + buf * (BM * 64);
    u16* Bd = Bs + buf * (128 * 64);
#pragma unroll
    for (int j = 0; j < BM / 32; ++j) {
      const int ch = w * (BM / 32) + j;
      gload16(Ag + (size_t)(ch * 8) * K + k0, Ad + ch * 512);
    }
#pragma unroll
    for (int j = 0; j < 4; ++j) {
      const int ch = w * 4 + j;
      gload16(Bg + (size_t)(ch * 8) * K + k0, Bd + ch * 512);
    }
  };

  auto compute = [&](const u16* Ab, const u16* Bb) {
#pragma unroll
    for (int kk = 0; kk < 2; ++kk) {
      s16x8 af[MW], bfv[NW];
#pragma unroll
      for (int m = 0; m < MW; ++m) af[m] = *(const s16x8*)(Ab + (wr * 64 + m * 16 + l16) * 64 + kk * 32 + lhi * 8);
#pragma unroll
      for (int n = 0; n < NW; ++n) bfv[n] = *(const s16x8*)(Bb + (wc * (16 * NW) + n * 16 + l16) * 64 + kk * 32 + lhi * 8);
#pragma unroll
      for (int m = 0; m < MW; ++m)
#pragma unroll
        for (int n = 0; n < NW; ++n)
          acc[m][n] = __builtin_amdgcn_mfma_f32_16x16x32_bf16(af[m], bfv[n], acc[m][n], 0, 0, 0);
    }
  };

  if constexpr (DBUF) {
    stage(0, 0);
    const int NT = K >> 6;
    for (int kt = 0; kt < NT; ++kt) {
      const int cur = kt & 1;
      __syncthreads();
      if (kt + 1 < NT) stage(cur ^ 1, (kt + 1) << 6);
      compute(As + cur * (BM * 64), Bs + cur * (128 * 64));
    }
  } else {
    for (int k0 = 0; k0 < K; k0 += 64) {
      __syncthreads();
      stage(0, k0);
      __syncthreads();
      compute(As, Bs);
    }
  }

#pragma unroll
  for (int n = 0; n < NW; ++n) {
    const int col = col0 + wc * (16 * NW) + n * 16 + l16;
    float bv = 0.f;
    if constexpr (HASB) bv = bias[col];
    float ra = 0.f, rc = 0.f;
    if constexpr (RESBN) bn_coef2(resS, resg, resb, col, ra, rc);
    float ssum = 0.f, ssq = 0.f;
#pragma unroll
    for (int m = 0; m < MW; ++m) {
      const int rbase = row0 + wr * 64 + m * 16 + lhi * 4;
#pragma unroll
      for (int r = 0; r < 4; ++r) {
        float v = acc[m][n][r] + bv;
        if constexpr (RELU) v = fmaxf(v, 0.f);
        const int row = rbase + r;
        const size_t idx = (size_t)row * Ncols + col;
        if constexpr (HASRES) {
          if constexpr (RESBN) v += fmaf(Res[idx], ra, rc);
          else v += Res[idx];
        }
        if constexpr (OUTF) Cf[idx] = v;
        if constexpr (OUTB) {
          if constexpr (SPLIT3) {
            const size_t ib = (size_t)(col >> 9) * QKVOFF + (size_t)row * DD + (col & 511);
            Cb[ib] = f2b(v);
          } else {
            Cb[idx] = f2b(v);
          }
        }
        if constexpr (STATS) { ssum += v; ssq += v * v; }
      }
    }
    if constexpr (STATS) {
      ssum += __shfl_xor(ssum, 16); ssq += __shfl_xor(ssq, 16);
      ssum += __shfl_xor(ssum, 32); ssq += __shfl_xor(ssq, 32);
      if (lhi == 0) {
        atomicAdd(&stats[col], ssum);
        atomicAdd(&stats[512 + col], ssq);
      }
    }
  }
}

// ---------------- attention pass 1: Z[q,k] = sum_n exp(scale * Q_[n,q,:].K_[n,k,:]) ----------------
__global__ __launch_bounds__(256) void k_attn_z(const u16* __restrict__ Q, const u16* __restrict__ Kt,
                                                float* __restrict__ Z) {
  const int t = threadIdx.x, lane = t & 63, w = t >> 6;
  const int l16 = lane & 15, lhi = lane >> 4;
  const int q0 = blockIdx.x * 64 + (w >> 1) * 32;
  const int k0 = blockIdx.y * 64 + (w & 1) * 32;
  const int n0 = blockIdx.z * 16;
  f32x4 zac[2][2] = {};
  for (int nn = 0; nn < 16; ++nn) {
    const int n = n0 + nn, h = n >> 4, b = n & 15;
    const size_t base = (size_t)b * LL * DD + (size_t)h * 32;
    s16x8 a[2], bb[2];
#pragma unroll
    for (int mi = 0; mi < 2; ++mi) a[mi] = *(const s16x8*)(Q + base + (size_t)(q0 + mi * 16 + l16) * DD + lhi * 8);
#pragma unroll
    for (int ni = 0; ni < 2; ++ni) bb[ni] = *(const s16x8*)(Kt + base + (size_t)(k0 + ni * 16 + l16) * DD + lhi * 8);
#pragma unroll
    for (int mi = 0; mi < 2; ++mi)
#pragma unroll
      for (int ni = 0; ni < 2; ++ni) {
        f32x4 z4 = {0.f, 0.f, 0.f, 0.f};
        f32x4 s = __builtin_amdgcn_mfma_f32_16x16x32_bf16(a[mi], bb[ni], z4, 0, 0, 0);
#pragma unroll
        for (int r = 0; r < 4; ++r) zac[mi][ni][r] += exp2f(s[r] * C2);
      }
  }
#pragma unroll
  for (int mi = 0; mi < 2; ++mi)
#pragma unroll
    for (int ni = 0; ni < 2; ++ni)
#pragma unroll
      for (int r = 0; r < 4; ++r)
        atomicAdd(&Z[(q0 + mi * 16 + lhi * 4 + r) * LL + k0 + ni * 16 + l16], zac[mi][ni][r]);
}

// ---------------- attention pass 2 (pv3): K/V LDS-resident; residual-BN coefs derived in prologue ----------------
__global__ __launch_bounds__(1024) void k_attn_pv3(const u16* __restrict__ Q, const u16* __restrict__ K,
                                                   const u16* __restrict__ V, const float* __restrict__ IZ,
                                                   const float* __restrict__ resS, const float* __restrict__ resg,
                                                   const float* __restrict__ resb, float* T,
                                                   float* __restrict__ stats) {
  __shared__ __align__(16) u16 Kl[512 * 40];   // rows padded 32->40 u16
  __shared__ __align__(16) u16 Vl[32 * 520];   // d-major rows padded 512->520 u16
  __shared__ __align__(16) u16 Pl[16][1024];   // per-wave P transpose buffer
  const int n = blockIdx.x, h = n >> 4, b = n & 15;
  const int t = threadIdx.x, lane = t & 63, w = t >> 6;
  const int l16 = lane & 15, lhi = lane >> 4;
  const size_t base = (size_t)b * LL * DD + (size_t)h * 32;

  // stage K: 2048 x 16B chunks (2 per thread)
#pragma unroll
  for (int j = 0; j < 2; ++j) {
    const int c = t + j * 1024;
    const int k = c >> 2, part = c & 3;
    const s16x8 v = *(const s16x8*)(K + base + (size_t)k * DD + part * 8);
    *(s16x8*)(Kl + k * 40 + part * 8) = v;
  }
  // stage V with in-flight transpose
#pragma unroll
  for (int j = 0; j < 2; ++j) {
    const int c = t + j * 1024;
    const int k = c >> 2, dp = c & 3;
    const s16x8 v = *(const s16x8*)(V + base + (size_t)k * DD + dp * 8);
#pragma unroll
    for (int jj = 0; jj < 8; ++jj) Vl[(dp * 8 + jj) * 520 + k] = (u16)v[jj];
  }
  // preload this wave's 2 Q fragments
  const int qbase = w * 32;
  s16x8 aqv[2];
#pragma unroll
  for (int qf = 0; qf < 2; ++qf)
    aqv[qf] = *(const s16x8*)(Q + base + (size_t)(qbase + qf * 16 + l16) * DD + lhi * 8);
  // residual BN coefs (derived from raw sums; outside the hot loop)
  float ra[2], rc[2];
#pragma unroll
  for (int dt = 0; dt < 2; ++dt)
    bn_coef2(resS, resg, resb, h * 32 + dt * 16 + l16, ra[dt], rc[dt]);
  __syncthreads();

  char* P = (char*)&Pl[w][0];
  const int wxor = (l16 & 7) << 4;
  const int wbase = l16 * 128 + lhi * 8;
  float ssum[2] = {0.f, 0.f}, ssq[2] = {0.f, 0.f};

#pragma unroll
  for (int qf = 0; qf < 2; ++qf) {
    const int q16 = qbase + qf * 16;
    const float* izrow = IZ + (size_t)(q16 + l16) * LL + lhi * 4;
    f32x4 oa[2] = {};
#pragma unroll
    for (int kt = 0; kt < 8; ++kt) {
      const int kb = kt * 64;
      f32x4 s[4]; float4 iz[4];
#pragma unroll
      for (int ks = 0; ks < 4; ++ks) {
        const s16x8 af = *(const s16x8*)(Kl + (kb + ks * 16 + l16) * 40 + lhi * 8);
        f32x4 z4 = {0.f, 0.f, 0.f, 0.f};
        s[ks] = __builtin_amdgcn_mfma_f32_16x16x32_bf16(af, aqv[qf], z4, 0, 0, 0);
        iz[ks] = *(const float4*)(izrow + kb + ks * 16);
      }
#pragma unroll
      for (int ks = 0; ks < 4; ++ks) {
        const float p0 = exp2f(s[ks][0] * C2) * iz[ks].x;
        const float p1 = exp2f(s[ks][1] * C2) * iz[ks].y;
        const float p2 = exp2f(s[ks][2] * C2) * iz[ks].z;
        const float p3 = exp2f(s[ks][3] * C2) * iz[ks].w;
        unsigned int pk0, pk1;
        asm("v_cvt_pk_bf16_f32 %0, %1, %2" : "=v"(pk0) : "v"(p0), "v"(p1));
        asm("v_cvt_pk_bf16_f32 %0, %1, %2" : "=v"(pk1) : "v"(p2), "v"(p3));
        u32x2 pw; pw[0] = pk0; pw[1] = pk1;
        *(u32x2*)(P + ((wbase + ks * 32) ^ wxor)) = pw;
      }
#pragma unroll
      for (int kc = 0; kc < 2; ++kc) {
        const s16x8 pa = *(const s16x8*)(P + ((l16 * 128 + kc * 64 + lhi * 16) ^ wxor));
#pragma unroll
        for (int dt = 0; dt < 2; ++dt) {
          const s16x8 bv = *(const s16x8*)(Vl + (dt * 16 + l16) * 520 + kb + kc * 32 + lhi * 8);
          oa[dt] = __builtin_amdgcn_mfma_f32_16x16x32_bf16(pa, bv, oa[dt], 0, 0, 0);
        }
      }
    }
#pragma unroll
    for (int dt = 0; dt < 2; ++dt)
#pragma unroll
      for (int r = 0; r < 4; ++r) {
        const size_t idx = (size_t)(b * LL + q16 + lhi * 4 + r) * DD + h * 32 + dt * 16 + l16;
        const float v = oa[dt][r] + fmaf(T[idx], ra[dt], rc[dt]);
        T[idx] = v;
        ssum[dt] += v; ssq[dt] += v * v;
      }
  }
#pragma unroll
  for (int dt = 0; dt < 2; ++dt) {
    float su = ssum[dt], sq = ssq[dt];
    su += __shfl_xor(su, 16); sq += __shfl_xor(sq, 16);
    su += __shfl_xor(su, 32); sq += __shfl_xor(sq, 32);
    if (lhi == 0) {
      const int col = h * 32 + dt * 16 + l16;
      atomicAdd(&stats[col], su);
      atomicAdd(&stats[512 + col], sq);
    }
  }
}

// ---------------- BatchNorm apply (coef derived per block from raw sums) ----------------
__global__ __launch_bounds__(256) void k_bn_applyB(const float* __restrict__ X, const float* __restrict__ S,
                                                   const float* __restrict__ g, const float* __restrict__ be,
                                                   u16* __restrict__ Yb) {
  __shared__ float co[1024];
  const int t = threadIdx.x;
#pragma unroll
  for (int j = 0; j < 2; ++j) {
    const int col = t + j * 256;
    float a, c; bn_coef2(S, g, be, col, a, c);
    co[col] = a; co[512 + col] = c;
  }
  __syncthreads();
  const int n4 = NROW * DD / 4;
  for (int i = blockIdx.x * 256 + t; i < n4; i += gridDim.x * 256) {
    const float4 xv = ((const float4*)X)[i];
    const int d = (i & 127) * 4;
    u16x4v o;
    o[0] = f2b(fmaf(xv.x, co[d + 0], co[512 + d + 0]));
    o[1] = f2b(fmaf(xv.y, co[d + 1], co[512 + d + 1]));
    o[2] = f2b(fmaf(xv.z, co[d + 2], co[512 + d + 2]));
    o[3] = f2b(fmaf(xv.w, co[d + 3], co[512 + d + 3]));
    ((u16x4v*)Yb)[i] = o;
  }
}

__global__ __launch_bounds__(256) void k_bn_applyF(const float* __restrict__ X, const float* __restrict__ S,
                                                   const float* __restrict__ g, const float* __restrict__ be,
                                                   float* __restrict__ Yf) {
  __shared__ float co[1024];
  const int t = threadIdx.x;
#pragma unroll
  for (int j = 0; j < 2; ++j) {
    const int col = t + j * 256;
    float a, c; bn_coef2(S, g, be, col, a, c);
    co[col] = a; co[512 + col] = c;
  }
  __syncthreads();
  const int n4 = NROW * DD / 4;
  for (int i = blockIdx.x * 256 + t; i < n4; i += gridDim.x * 256) {
    const float4 xv = ((const float4*)X)[i];
    const int d = (i & 127) * 4;
    float4 o;
    o.x = fmaf(xv.x, co[d + 0], co[512 + d + 0]);
    o.y = fmaf(xv.y, co[d + 1], co[512 + d + 1]);
    o.z = fmaf(xv.z, co[d + 2], co[512 + d + 2]);
    o.w = fmaf(xv.w, co[d + 3], co[512 + d + 3]);
    ((float4*)Yf)[i] = o;
  }
}

// ---------------- host launch ----------------
extern "C" void kernel_launch(void* const* d_in, const int* in_sizes, int n_in,
                              void* d_out, int out_size, void* d_ws, size_t ws_size,
                              hipStream_t stream) {
  const float* x    = (const float*)d_in[0];
  const float* emb  = (const float*)d_in[1];
  const float* bn2g = (const float*)d_in[2];
  const float* bn2b = (const float*)d_in[3];
  const float* Wq   = (const float*)d_in[4];
  const float* bq   = (const float*)d_in[5];
  const float* Wk   = (const float*)d_in[6];
  const float* bkp  = (const float*)d_in[7];
  const float* Wv   = (const float*)d_in[8];
  const float* bvp  = (const float*)d_in[9];
  const float* bnag = (const float*)d_in[10];
  const float* bnab = (const float*)d_in[11];
  const float* W1   = (const float*)d_in[12];
  const float* b1   = (const float*)d_in[13];
  const float* W2   = (const float*)d_in[14];
  const float* b2   = (const float*)d_in[15];
  const float* bnfg = (const float*)d_in[16];
  const float* bnfb = (const float*)d_in[17];

  char* p = (char*)d_ws;
  auto alloc = [&](size_t bytes) { char* r = p; p += (bytes + 255) & ~(size_t)255; return r; };
  u16*   xb    = (u16*)alloc((size_t)NROW * DD * 2);
  u16*   encB  = (u16*)alloc((size_t)NROW * DD * 2);
  float* tF    = (float*)alloc((size_t)NROW * DD * 4);
  u16*   qkv   = (u16*)alloc((size_t)3 * NROW * DD * 2); // Q | K | V
  u16*   h1    = (u16*)alloc((size_t)NROW * FF_ * 2);
  float* Z     = (float*)alloc((size_t)LL * LL * 4);
  float* sums  = (float*)alloc(7 * 1024 * 4);  // 7 BN stages: bn2, (bna,bnf) x3
  float* bqkv  = (float*)alloc(1536 * 4);
  u16*   embT  = (u16*)alloc((size_t)DD * DD * 2);
  u16*   wqkvT = (u16*)alloc((size_t)3 * DD * DD * 2);
  u16*   w1T   = (u16*)alloc((size_t)DD * FF_ * 2);
  u16*   w2T   = (u16*)alloc((size_t)FF_ * DD * 2);
  if ((size_t)(p - (char*)d_ws) > ws_size) return;

  float* s0 = sums;
  auto sa = [&](int i) { return sums + (1 + 2 * i) * 1024; };
  auto sf = [&](int i) { return sums + (2 + 2 * i) * 1024; };

  k_zero<<<28, 256, 0, stream>>>(sums, 7 * 1024);
  k_f32_to_bf16<<<2048, 256, 0, stream>>>(x, xb, NROW * DD / 4);
  k_wtrans<<<dim3(16, 16), 256, 0, stream>>>(emb, embT, DD, DD);
  // emb conv (no bias), BM=64, dbuf, stats -> s0
  k_gemm<64, 1, 0, 0, 0, 0, 1, 0, 1, 0><<<dim3(128, 4), 256, 0, stream>>>(
      xb, embT, nullptr, nullptr, nullptr, nullptr, nullptr, tF, nullptr, s0, DD, DD);
  k_bn_applyB<<<2048, 256, 0, stream>>>(tF, s0, bn2g, bn2b, encB);

  for (int i = 0; i < 3; ++i) {
    const float* Sprev = (i == 0) ? s0 : sf(i - 1);
    const float* gprev = (i == 0) ? bn2g : bnfg + (i - 1) * DD;
    const float* bprev = (i == 0) ? bn2b : bnfb + (i - 1) * DD;
    k_wtrans<<<dim3(16, 16), 256, 0, stream>>>(Wq + (size_t)i * DD * DD, wqkvT, DD, DD);
    k_wtrans<<<dim3(16, 16), 256, 0, stream>>>(Wk + (size_t)i * DD * DD, wqkvT + (size_t)512 * DD, DD, DD);
    k_wtrans<<<dim3(16, 16), 256, 0, stream>>>(Wv + (size_t)i * DD * DD, wqkvT + (size_t)1024 * DD, DD, DD);
    k_catbias<<<6, 256, 0, stream>>>(bq + i * DD, bkp + i * DD, bvp + i * DD, bqkv);
    // QKV GEMM: BM=128, dbuf, split-3 bf16 out
    k_gemm<128, 1, 1, 1, 0, 0, 0, 1, 0, 1><<<dim3(64, 12), 256, 0, stream>>>(
        encB, wqkvT, bqkv, nullptr, nullptr, nullptr, nullptr, nullptr, qkv, nullptr, DD, 1536);
    k_zero<<<1024, 256, 0, stream>>>(Z, LL * LL);
    k_attn_z<<<dim3(8, 8, 16), 256, 0, stream>>>(qkv, qkv + QKVOFF, Z);
    k_recip<<<1024, 256, 0, stream>>>(Z, LL * LL);
    // pv3: residual = BN(prev) from raw sums; stats -> sa(i)
    k_attn_pv3<<<256, 1024, 0, stream>>>(qkv, qkv + QKVOFF, qkv + 2 * QKVOFF, Z,
                                         Sprev, gprev, bprev, tF, sa(i));
    k_bn_applyB<<<2048, 256, 0, stream>>>(tF, sa(i), bnag + i * DD, bnab + i * DD, encB);
    k_wtrans<<<dim3(16, 64), 256, 0, stream>>>(W1 + (size_t)i * DD * FF_, w1T, DD, FF_);
    // FF1: BM=128, dbuf
    k_gemm<128, 1, 1, 1, 0, 0, 0, 1, 0, 0><<<dim3(64, 16), 256, 0, stream>>>(
        encB, w1T, b1 + i * FF_, nullptr, nullptr, nullptr, nullptr, nullptr, h1, nullptr, DD, FF_);
    k_wtrans<<<dim3(64, 16), 256, 0, stream>>>(W2 + (size_t)i * FF_ * DD, w2T, FF_, DD);
    // FF2: BM=64, dbuf, residual = BN_a(tF) in-place, stats -> sf(i)
    k_gemm<64, 1, 0, 1, 1, 1, 1, 0, 1, 0><<<dim3(128, 4), 256, 0, stream>>>(
        h1, w2T, b2 + i * DD, tF, sa(i), bnag + i * DD, bnab + i * DD, tF, nullptr, sf(i), FF_, DD);
    if (i == 2) k_bn_applyF<<<2048, 256, 0, stream>>>(tF, sf(i), bnfg + i * DD, bnfb + i * DD, (float*)d_out);
    else        k_bn_applyB<<<2048, 256, 0, stream>>>(tF, sf(i), bnfg + i * DD, bnfb + i * DD, encB);
  }
}